// Round 12
// baseline (1073.239 us; speedup 1.0000x reference)
//
#include <hip/hip_runtime.h>
#include <math.h>

// ---------------- problem constants ----------------
constexpr int NB = 32;    // B
constexpr int NM = 64;    // M
constexpr int NNV = 65;   // NV
constexpr int NH = 960;   // H
constexpr int ND = 480;   // D
constexpr float ATT_SCALE = 0.045643546458763842f;  // D^-0.5

constexpr int OF_Pq = 0;
constexpr int OF_cq = 4320;
constexpr int OF_Q2 = 5760;
constexpr int OF_V2 = OF_Q2 + 2*1440;
constexpr int OF_dq = 10080;
constexpr int OF_dv = OF_dq + 2*480;
constexpr int OF_S  = 11520;
constexpr int OF_u  = 11529;
constexpr int OF_r  = 11532;
constexpr int OF_w  = 11535;
constexpr int FOLD_SZ = 11552;

typedef unsigned short u16;
typedef float f32x4 __attribute__((ext_vector_type(4)));
typedef short s16x8 __attribute__((ext_vector_type(8)));

__device__ __forceinline__ float wave_sum(float v) {
#pragma unroll
  for (int d = 32; d; d >>= 1) v += __shfl_xor(v, d);
  return v;
}

__device__ __forceinline__ void split_bf16(float x, short& hi, short& lo) {
  union { float f; unsigned u; } a; a.f = x;
  unsigned uh = a.u + 0x7fffu + ((a.u >> 16) & 1u);
  hi = (short)(uh >> 16);
  union { unsigned u; float f; } b; b.u = ((unsigned)(unsigned short)hi) << 16;
  union { float f; unsigned u; } c; c.f = x - b.f;
  unsigned ul = c.u + 0x7fffu + ((c.u >> 16) & 1u);
  lo = (short)(ul >> 16);
}

// transpose-convert: dst[z][n][k] = split(src[z][k][n]) for 5 planes (bt_W 0..2, bi_W 0..1)
__global__ __launch_bounds__(256) void k_cvtT(
    const float* __restrict__ btW, const float* __restrict__ biW,
    u16* __restrict__ wtHi, u16* __restrict__ wtLo)
{
  __shared__ float s[32][33];
  const int z = blockIdx.z;
  const float* src = (z < 3) ? (btW + (size_t)z * ND * ND) : (biW + (size_t)(z - 3) * ND * ND);
  u16* dh = wtHi + (size_t)z * ND * ND;
  u16* dl = wtLo + (size_t)z * ND * ND;
  const int k0 = blockIdx.y * 32, n0 = blockIdx.x * 32;
  const int tx = threadIdx.x & 31, ty = threadIdx.x >> 5;
#pragma unroll
  for (int q = 0; q < 4; ++q)
    s[ty + q * 8][tx] = src[(size_t)(k0 + ty + q * 8) * ND + n0 + tx];
  __syncthreads();
#pragma unroll
  for (int q = 0; q < 4; ++q) {
    float v = s[tx][ty + q * 8];
    short h, l; split_bf16(v, h, l);
    size_t di = (size_t)(n0 + ty + q * 8) * ND + k0 + tx;
    dh[di] = (u16)h; dl[di] = (u16)l;
  }
}

// ---------------- MFMA split-bf16 projection GEMM (6 configs, XCD swizzled) + key plane epilogue ----------------
struct ProjCfg {
  const float* X; const float* W; const float* bias; float* C;
  u16* pH; u16* pL;
  int R; int x0; int rpb; int xbs;
};
struct Proj6 { ProjCfg c[6]; };

constexpr int KP = 40;   // padded k stride (ushorts)

__global__ __launch_bounds__(256) void k_projM(Proj6 P, int K)
{
  __shared__ u16 As_hi[64][KP], As_lo[64][KP];
  __shared__ u16 Bs_hi[48][KP], Bs_lo[48][KP];
  int p = blockIdx.x, total = gridDim.x;
  int q = total >> 3, r = total & 7;
  int xk = p & 7, idx = p >> 3;
  int lgc = (xk < r) ? (xk * (q + 1) + idx) : (r * (q + 1) + (xk - r) * q + idx);
  int mp = lgc / 10, nx = lgc - mp * 10;
  ProjCfg cfg; int my;
  if      (mp < 32)  { cfg = P.c[0]; my = mp; }
  else if (mp < 65)  { cfg = P.c[1]; my = mp - 32; }
  else if (mp < 97)  { cfg = P.c[2]; my = mp - 65; }
  else if (mp < 129) { cfg = P.c[3]; my = mp - 97; }
  else if (mp < 161) { cfg = P.c[4]; my = mp - 129; }
  else               { cfg = P.c[5]; my = mp - 161; }
  const int m0 = my * 64, n0 = nx * 48;
  const int tid = threadIdx.x;
  const int l6 = tid & 63, w = tid >> 6;
  const int lr = tid >> 2, kc = (tid & 3) * 8;
  const float* Arow = nullptr;
  {
    int rr = m0 + lr;
    if (rr < cfg.R) {
      int b = rr / cfg.rpb, r2 = rr - b * cfg.rpb;
      Arow = cfg.X + (size_t)b * cfg.xbs + (size_t)(cfg.x0 + r2) * K;
    }
  }
  const float* Brow = (lr < 48) ? (cfg.W + (size_t)(n0 + lr) * K) : nullptr;
  const int fr = l6 & 15, fk = (l6 >> 4) * 8;
  f32x4 acc0 = {0.f, 0.f, 0.f, 0.f}, acc1 = acc0, acc2 = acc0;
  for (int k0 = 0; k0 < K; k0 += 32) {
    float xs[8] = {0.f, 0.f, 0.f, 0.f, 0.f, 0.f, 0.f, 0.f};
    if (Arow) {
      float4 a0 = *(const float4*)(Arow + k0 + kc);
      float4 a1 = *(const float4*)(Arow + k0 + kc + 4);
      xs[0] = a0.x; xs[1] = a0.y; xs[2] = a0.z; xs[3] = a0.w;
      xs[4] = a1.x; xs[5] = a1.y; xs[6] = a1.z; xs[7] = a1.w;
    }
    s16x8 vh, vl;
#pragma unroll
    for (int e = 0; e < 8; ++e) { short h, lo2; split_bf16(xs[e], h, lo2); vh[e] = h; vl[e] = lo2; }
    *(s16x8*)&As_hi[lr][kc] = vh;
    *(s16x8*)&As_lo[lr][kc] = vl;
    if (Brow) {
      float4 b0 = *(const float4*)(Brow + k0 + kc);
      float4 b1 = *(const float4*)(Brow + k0 + kc + 4);
      float ys[8] = {b0.x, b0.y, b0.z, b0.w, b1.x, b1.y, b1.z, b1.w};
      s16x8 wh, wl;
#pragma unroll
      for (int e = 0; e < 8; ++e) { short h, lo2; split_bf16(ys[e], h, lo2); wh[e] = h; wl[e] = lo2; }
      *(s16x8*)&Bs_hi[lr][kc] = wh;
      *(s16x8*)&Bs_lo[lr][kc] = wl;
    }
    __syncthreads();
    s16x8 ah = *(const s16x8*)&As_hi[16 * w + fr][fk];
    s16x8 al = *(const s16x8*)&As_lo[16 * w + fr][fk];
    {
      s16x8 bh = *(const s16x8*)&Bs_hi[fr][fk];
      s16x8 bl = *(const s16x8*)&Bs_lo[fr][fk];
      acc0 = __builtin_amdgcn_mfma_f32_16x16x32_bf16(ah, bh, acc0, 0, 0, 0);
      acc0 = __builtin_amdgcn_mfma_f32_16x16x32_bf16(ah, bl, acc0, 0, 0, 0);
      acc0 = __builtin_amdgcn_mfma_f32_16x16x32_bf16(al, bh, acc0, 0, 0, 0);
    }
    {
      s16x8 bh = *(const s16x8*)&Bs_hi[16 + fr][fk];
      s16x8 bl = *(const s16x8*)&Bs_lo[16 + fr][fk];
      acc1 = __builtin_amdgcn_mfma_f32_16x16x32_bf16(ah, bh, acc1, 0, 0, 0);
      acc1 = __builtin_amdgcn_mfma_f32_16x16x32_bf16(ah, bl, acc1, 0, 0, 0);
      acc1 = __builtin_amdgcn_mfma_f32_16x16x32_bf16(al, bh, acc1, 0, 0, 0);
    }
    {
      s16x8 bh = *(const s16x8*)&Bs_hi[32 + fr][fk];
      s16x8 bl = *(const s16x8*)&Bs_lo[32 + fr][fk];
      acc2 = __builtin_amdgcn_mfma_f32_16x16x32_bf16(ah, bh, acc2, 0, 0, 0);
      acc2 = __builtin_amdgcn_mfma_f32_16x16x32_bf16(ah, bl, acc2, 0, 0, 0);
      acc2 = __builtin_amdgcn_mfma_f32_16x16x32_bf16(al, bh, acc2, 0, 0, 0);
    }
    __syncthreads();
  }
#pragma unroll
  for (int c = 0; c < 3; ++c) {
    f32x4 av = (c == 0) ? acc0 : (c == 1) ? acc1 : acc2;
    int n = n0 + 16 * c + fr;
    float bv = cfg.bias[n];
#pragma unroll
    for (int g = 0; g < 4; ++g) {
      int rr = m0 + 16 * w + (l6 >> 4) * 4 + g;
      if (rr < cfg.R) {
        float v = av[g] + bv;
        size_t di = (size_t)rr * ND + n;
        cfg.C[di] = v;
        if (cfg.pH) {
          short h, lo2; split_bf16(v, h, lo2);
          cfg.pH[di] = (u16)h; cfg.pL[di] = (u16)lo2;
        }
      }
    }
  }
}

// ---------------- MFMA tmp GEMM: plane-based A (key u16) and B (W^T u16) ----------------
__global__ __launch_bounds__(256) void k_tmpM(
    const u16* __restrict__ KH, const u16* __restrict__ KL,
    const u16* __restrict__ WtH, const u16* __restrict__ WtL,
    float* __restrict__ T, int O,
    const float* __restrict__ typeSrc, const float* __restrict__ keyMask,
    float* __restrict__ km2, int doType)
{
  __shared__ u16 As_hi[64][KP], As_lo[64][KP];
  __shared__ u16 Bs_hi[48][KP], Bs_lo[48][KP];
  const int n0 = blockIdx.x * 48;
  const int o = blockIdx.y, b = blockIdx.z;
  const int tid = threadIdx.x;
  if (doType && blockIdx.x == 0 && blockIdx.y == 0 && tid < NM) {
    const float* p = typeSrc + ((size_t)(b * NM + tid)) * NNV * 3;
    float l0 = p[0], l1 = p[1], l2 = p[2];
    int arg = 0; float best = l0;
    if (l1 > best) { best = l1; arg = 1; }
    if (l2 > best) { arg = 2; }
    km2[b * NM + tid] = (keyMask[b * NM + tid] != 0.f && arg == 1) ? 1.f : 0.f;
  }
  const int l6 = tid & 63, w = tid >> 6;
  const int lr = tid >> 2, kc = (tid & 3) * 8;
  const size_t aoff = ((size_t)b * NM + lr) * ND;
  const bool bok = lr < 48;
  const size_t boff = ((size_t)o * ND + n0 + (bok ? lr : 0)) * ND;
  const int fr = l6 & 15, fk = (l6 >> 4) * 8;
  f32x4 acc0 = {0.f, 0.f, 0.f, 0.f}, acc1 = acc0, acc2 = acc0;
  for (int k0 = 0; k0 < ND; k0 += 32) {
    *(s16x8*)&As_hi[lr][kc] = *(const s16x8*)(KH + aoff + k0 + kc);
    *(s16x8*)&As_lo[lr][kc] = *(const s16x8*)(KL + aoff + k0 + kc);
    if (bok) {
      *(s16x8*)&Bs_hi[lr][kc] = *(const s16x8*)(WtH + boff + k0 + kc);
      *(s16x8*)&Bs_lo[lr][kc] = *(const s16x8*)(WtL + boff + k0 + kc);
    }
    __syncthreads();
    s16x8 ah = *(const s16x8*)&As_hi[16 * w + fr][fk];
    s16x8 al = *(const s16x8*)&As_lo[16 * w + fr][fk];
    {
      s16x8 bh = *(const s16x8*)&Bs_hi[fr][fk];
      s16x8 bl = *(const s16x8*)&Bs_lo[fr][fk];
      acc0 = __builtin_amdgcn_mfma_f32_16x16x32_bf16(ah, bh, acc0, 0, 0, 0);
      acc0 = __builtin_amdgcn_mfma_f32_16x16x32_bf16(ah, bl, acc0, 0, 0, 0);
      acc0 = __builtin_amdgcn_mfma_f32_16x16x32_bf16(al, bh, acc0, 0, 0, 0);
    }
    {
      s16x8 bh = *(const s16x8*)&Bs_hi[16 + fr][fk];
      s16x8 bl = *(const s16x8*)&Bs_lo[16 + fr][fk];
      acc1 = __builtin_amdgcn_mfma_f32_16x16x32_bf16(ah, bh, acc1, 0, 0, 0);
      acc1 = __builtin_amdgcn_mfma_f32_16x16x32_bf16(ah, bl, acc1, 0, 0, 0);
      acc1 = __builtin_amdgcn_mfma_f32_16x16x32_bf16(al, bh, acc1, 0, 0, 0);
    }
    {
      s16x8 bh = *(const s16x8*)&Bs_hi[32 + fr][fk];
      s16x8 bl = *(const s16x8*)&Bs_lo[32 + fr][fk];
      acc2 = __builtin_amdgcn_mfma_f32_16x16x32_bf16(ah, bh, acc2, 0, 0, 0);
      acc2 = __builtin_amdgcn_mfma_f32_16x16x32_bf16(ah, bl, acc2, 0, 0, 0);
      acc2 = __builtin_amdgcn_mfma_f32_16x16x32_bf16(al, bh, acc2, 0, 0, 0);
    }
    __syncthreads();
  }
  float* C = T + ((size_t)(b * O + o) * NM) * ND;
#pragma unroll
  for (int c = 0; c < 3; ++c) {
    f32x4 av = (c == 0) ? acc0 : (c == 1) ? acc1 : acc2;
    int n = n0 + 16 * c + fr;
#pragma unroll
    for (int g = 0; g < 4; ++g) {
      int rr = 16 * w + (l6 >> 4) * 4 + g;
      C[(size_t)rr * ND + n] = av[g];
    }
  }
}

// fused bilinear + attention(MODE0) per (b,m) with parallel softmax
template <int O, int NVX>
__global__ __launch_bounds__(256) void k_bilatt0(
    const float* __restrict__ T, const float* __restrict__ Val,
    const float* __restrict__ linK, const float* __restrict__ linV,
    const float* __restrict__ lb, const float* __restrict__ F,
    const float* __restrict__ km, const float* __restrict__ vm,
    int vmOff, int vmStride, float* __restrict__ Y1)
{
  __shared__ float Ls[NVX][3];
  __shared__ float STs[NVX][3];
  __shared__ float hs[NVX], gs[NVX], mkj[NVX];
  __shared__ float Pm[NVX][66];
  __shared__ float rmx[NVX][3];
  __shared__ float rsum[NVX][3];
  __shared__ float ry[NVX][3][3];
  __shared__ float lvs[NVX][3];
  const int b = blockIdx.x >> 6, m = blockIdx.x & 63;
  const int tid = threadIdx.x;
  const int lane = tid & 63, w = tid >> 6;

  for (int j = tid; j < NVX; j += 256) {
    mkj[j] = vm[b * vmStride + vmOff + j];
#pragma unroll
    for (int o = 0; o < O; ++o) lvs[j][o] = linV[((size_t)b * NVX + j) * O + o];
  }
  float4 tsr[O][2];
#pragma unroll
  for (int o = 0; o < O; ++o) {
    const float4* trow = (const float4*)(T + (((size_t)b * O + o) * NM + m) * (size_t)ND);
    tsr[o][0] = trow[lane];
    tsr[o][1] = (lane < 56) ? trow[64 + lane] : make_float4(0.f, 0.f, 0.f, 0.f);
  }
  float lk[O];
#pragma unroll
  for (int o = 0; o < O; ++o) lk[o] = linK[((size_t)b * NM + m) * O + o] + lb[o];
  const float gm = km[b * NM + m];
  const bool gz = (gm == 0.f);

  for (int n = w; n < NVX; n += 4) {
    const float4* vrow = (const float4*)(Val + ((size_t)b * NVX + n) * (size_t)ND);
    float4 v0 = vrow[lane];
    float4 v1 = (lane < 56) ? vrow[64 + lane] : make_float4(0.f, 0.f, 0.f, 0.f);
    float a[3] = {0.f, 0.f, 0.f};
#pragma unroll
    for (int o = 0; o < O; ++o) {
      a[o] = v0.x * tsr[o][0].x + v0.y * tsr[o][0].y + v0.z * tsr[o][0].z + v0.w * tsr[o][0].w
           + v1.x * tsr[o][1].x + v1.y * tsr[o][1].y + v1.z * tsr[o][1].z + v1.w * tsr[o][1].w;
    }
#pragma unroll
    for (int o = 0; o < O; ++o) a[o] = wave_sum(a[o]);
    if (lane == 0) {
#pragma unroll
      for (int o = 0; o < O; ++o) Ls[n][o] = a[o] + lk[o] + lvs[n][o];
      if (O == 2) Ls[n][2] = 0.f;
    }
  }
  __syncthreads();
  const float* Sm = F + OF_S;
  const float u0 = F[OF_u], u1 = F[OF_u + 1], u2 = F[OF_u + 2];
  const float r0 = F[OF_r], r1 = F[OF_r + 1], r2 = F[OF_r + 2];
  const float wc = F[OF_w];
  if (tid < NVX) {
    int j = tid;
    float t0 = Ls[j][0], t1 = Ls[j][1], t2 = Ls[j][2];
    STs[j][0] = t0 * Sm[0] + t1 * Sm[3] + t2 * Sm[6];
    STs[j][1] = t0 * Sm[1] + t1 * Sm[4] + t2 * Sm[7];
    STs[j][2] = t0 * Sm[2] + t1 * Sm[5] + t2 * Sm[8];
    hs[j] = t0 * u0 + t1 * u1 + t2 * u2;
    gs[j] = t0 * r0 + t1 * r1 + t2 * r2;
  }
  __syncthreads();
  const bool act = tid < NVX * 3;
  int i = 0, qq = 0, jlo = 0, jhi = 0;
  float st0 = 0, st1 = 0, st2 = 0, hi = 0;
  bool rowz = true;
  if (act) {
    i = tid / 3; qq = tid - i * 3;
    jlo = qq * 22; jhi = (jlo + 22 < NVX) ? jlo + 22 : NVX;
    st0 = STs[i][0]; st1 = STs[i][1]; st2 = STs[i][2]; hi = hs[i];
    rowz = gz || (mkj[i] == 0.f);
    float mx = -3.0e38f;
    for (int j = jlo; j < jhi; ++j) {
      float s = st0 * Ls[j][0] + st1 * Ls[j][1] + hi + gs[j] + wc;
      if (O == 3) s += st2 * Ls[j][2];
      s = (rowz || mkj[j] == 0.f) ? -10000.f : ATT_SCALE * s;
      Pm[i][j] = s;
      mx = fmaxf(mx, s);
    }
    rmx[i][qq] = mx;
  }
  __syncthreads();
  if (act) {
    float mx = fmaxf(fmaxf(rmx[i][0], rmx[i][1]), rmx[i][2]);
    float sum = 0.f, y0 = 0.f, y1 = 0.f, y2 = 0.f;
    for (int j = jlo; j < jhi; ++j) {
      float pp = __expf(Pm[i][j] - mx);
      sum += pp; y0 += pp * Ls[j][0]; y1 += pp * Ls[j][1];
      if (O == 3) y2 += pp * Ls[j][2];
    }
    rsum[i][qq] = sum; ry[i][qq][0] = y0; ry[i][qq][1] = y1; ry[i][qq][2] = y2;
  }
  __syncthreads();
  if (tid < NVX) {
    int ii = tid;
    float sum = rsum[ii][0] + rsum[ii][1] + rsum[ii][2];
    float y0 = ry[ii][0][0] + ry[ii][1][0] + ry[ii][2][0];
    float y1 = ry[ii][0][1] + ry[ii][1][1] + ry[ii][2][1];
    float y2 = ry[ii][0][2] + ry[ii][1][2] + ry[ii][2][2];
    float inv = 1.f / sum;
    size_t ob = (((size_t)b * NM + m) * NVX + ii) * O;
    Y1[ob + 0] = y0 * inv;
    Y1[ob + 1] = y1 * inv;
    if (O == 3) Y1[ob + 2] = y2 * inv;
  }
}

// fused attention(MODE1) + value-update + linV per (b,n), parallel softmax
template <int O, int NVX>
__global__ __launch_bounds__(256) void k_att1vupd(
    const float* __restrict__ Y1, float* __restrict__ Y2,
    const float* __restrict__ F,
    const float* __restrict__ km, const float* __restrict__ vm,
    int vmOff, int vmStride,
    float* __restrict__ valb, const float* __restrict__ lw,
    float* __restrict__ linV)
{
  __shared__ float Ys1[NM][3];
  __shared__ float STs[NM][3];
  __shared__ float hs[NM], gs[NM], mkm[NM];
  __shared__ float Pm[NM][66];
  __shared__ float rmx[NM][3];
  __shared__ float rsum[NM][3];
  __shared__ float ry[NM][3][3];
  __shared__ float Ys2[NM][3];
  __shared__ float vrow[ND];
  const int b = blockIdx.x / NVX, n = blockIdx.x - b * NVX;
  const int tid = threadIdx.x;
  for (int u = tid; u < NM * O; u += 256) {
    int mm = u % NM, o = u / NM;
    Ys1[mm][o] = Y1[(((size_t)b * NM + mm) * NVX + n) * O + o];
  }
  if (tid < NM) {
    mkm[tid] = km[b * NM + tid];
    if (O == 2) Ys1[tid][2] = 0.f;
  }
  const float gm = vm[b * vmStride + vmOff + n];
  const bool gz = (gm == 0.f);
  __syncthreads();
  const float* Sm = F + OF_S + 16;
  const float u0 = F[OF_u + 16], u1 = F[OF_u + 17], u2 = F[OF_u + 18];
  const float r0 = F[OF_r + 16], r1 = F[OF_r + 17], r2 = F[OF_r + 18];
  const float wc = F[OF_w + 16];
  if (tid < NM) {
    int j = tid;
    float t0 = Ys1[j][0], t1 = Ys1[j][1], t2 = Ys1[j][2];
    STs[j][0] = t0 * Sm[0] + t1 * Sm[3] + t2 * Sm[6];
    STs[j][1] = t0 * Sm[1] + t1 * Sm[4] + t2 * Sm[7];
    STs[j][2] = t0 * Sm[2] + t1 * Sm[5] + t2 * Sm[8];
    hs[j] = t0 * u0 + t1 * u1 + t2 * u2;
    gs[j] = t0 * r0 + t1 * r1 + t2 * r2;
  }
  __syncthreads();
  const bool act = tid < NM * 3;
  int i = 0, qq = 0, jlo = 0, jhi = 0;
  float st0 = 0, st1 = 0, st2 = 0, hi = 0;
  bool rowz = true;
  if (act) {
    i = tid / 3; qq = tid - i * 3;
    jlo = qq * 22; jhi = (jlo + 22 < NM) ? jlo + 22 : NM;
    st0 = STs[i][0]; st1 = STs[i][1]; st2 = STs[i][2]; hi = hs[i];
    rowz = gz || (mkm[i] == 0.f);
    float mx = -3.0e38f;
    for (int j = jlo; j < jhi; ++j) {
      float s = st0 * Ys1[j][0] + st1 * Ys1[j][1] + hi + gs[j] + wc;
      if (O == 3) s += st2 * Ys1[j][2];
      s = (rowz || mkm[j] == 0.f) ? -10000.f : ATT_SCALE * s;
      Pm[i][j] = s;
      mx = fmaxf(mx, s);
    }
    rmx[i][qq] = mx;
  }
  __syncthreads();
  if (act) {
    float mx = fmaxf(fmaxf(rmx[i][0], rmx[i][1]), rmx[i][2]);
    float sum = 0.f, y0 = 0.f, y1 = 0.f, y2 = 0.f;
    for (int j = jlo; j < jhi; ++j) {
      float pp = __expf(Pm[i][j] - mx);
      sum += pp; y0 += pp * Ys1[j][0]; y1 += pp * Ys1[j][1];
      if (O == 3) y2 += pp * Ys1[j][2];
    }
    rsum[i][qq] = sum; ry[i][qq][0] = y0; ry[i][qq][1] = y1; ry[i][qq][2] = y2;
  }
  __syncthreads();
  if (tid < NM) {
    int ii = tid;
    float sum = rsum[ii][0] + rsum[ii][1] + rsum[ii][2];
    float y0 = ry[ii][0][0] + ry[ii][1][0] + ry[ii][2][0];
    float y1 = ry[ii][0][1] + ry[ii][1][1] + ry[ii][2][1];
    float y2 = ry[ii][0][2] + ry[ii][1][2] + ry[ii][2][2];
    float inv = 1.f / sum;
    y0 *= inv; y1 *= inv; y2 *= inv;
    size_t ob = (((size_t)b * NVX + n) * NM + ii) * O;
    Y2[ob + 0] = y0; Y2[ob + 1] = y1;
    if (O == 3) Y2[ob + 2] = y2;
    Ys2[ii][0] = y0; Ys2[ii][1] = y1; Ys2[ii][2] = (O == 3) ? y2 : 0.f;
  }
  __syncthreads();
  const float* V2 = F + OF_V2;
  const float* dv = F + OF_dv;
  for (int d = tid; d < ND; d += 256) {
    float v0 = V2[d], v1 = V2[ND + d], v2 = (O == 3) ? V2[2 * ND + d] : 0.f;
    float mx = -3.0e38f;
    for (int j = 0; j < NM; ++j) {
      float s = Ys2[j][0] * v0 + Ys2[j][1] * v1;
      if (O == 3) s += Ys2[j][2] * v2;
      mx = fmaxf(mx, s);
    }
    size_t di = ((size_t)b * NVX + n) * ND + d;
    float nv = valb[di] + mx + dv[d];
    valb[di] = nv;
    vrow[d] = nv;
  }
  __syncthreads();
  const int wv = tid >> 6, lane = tid & 63;
  if (wv < O) {
    float acc = 0.f;
    for (int d = lane; d < ND; d += 64) acc += vrow[d] * lw[(size_t)wv * 2 * ND + ND + d];
    acc = wave_sum(acc);
    if (lane == 0) linV[((size_t)b * NVX + n) * O + wv] = acc;
  }
}

// fused key-update + linK + key plane refresh per (b,m)
template <int O, int NVX>
__global__ __launch_bounds__(256) void k_kupd(
    const float* __restrict__ Y2, const float* __restrict__ F,
    float* __restrict__ keyb, const float* __restrict__ lw,
    float* __restrict__ linK, u16* __restrict__ kH, u16* __restrict__ kL)
{
  __shared__ float Ys[NVX][3];
  __shared__ float krow[ND];
  const int b = blockIdx.x >> 6, m = blockIdx.x & 63;
  const int tid = threadIdx.x;
  for (int u = tid; u < NVX * O; u += 256) {
    int j = u % NVX, o = u / NVX;
    Ys[j][o] = Y2[(((size_t)b * NVX + j) * NM + m) * O + o];
  }
  __syncthreads();
  const float* V2 = F + OF_V2;
  const float* dv = F + OF_dv;
  for (int d = tid; d < ND; d += 256) {
    float v0 = V2[d], v1 = V2[ND + d], v2 = (O == 3) ? V2[2 * ND + d] : 0.f;
    float mx = -3.0e38f;
    for (int j = 0; j < NVX; ++j) {
      float s = Ys[j][0] * v0 + Ys[j][1] * v1;
      if (O == 3) s += Ys[j][2] * v2;
      mx = fmaxf(mx, s);
    }
    size_t di = ((size_t)b * NM + m) * ND + d;
    float nv = keyb[di] + mx + dv[d];
    keyb[di] = nv;
    krow[d] = nv;
    short h, l; split_bf16(nv, h, l);
    kH[di] = (u16)h; kL[di] = (u16)l;
  }
  __syncthreads();
  const int wv = tid >> 6, lane = tid & 63;
  if (wv < O) {
    float acc = 0.f;
    for (int d = lane; d < ND; d += 64) acc += krow[d] * lw[(size_t)wv * 2 * ND + d];
    acc = wave_sum(acc);
    if (lane == 0) linK[((size_t)b * NM + m) * O + wv] = acc;
  }
}

// final bilinear with mask, register-ts + global Val
template <int O, int NVX>
__global__ __launch_bounds__(256) void k_bilfin(
    const float* __restrict__ T, const float* __restrict__ Val,
    const float* __restrict__ linK, const float* __restrict__ linV,
    const float* __restrict__ lb, const float* __restrict__ km,
    const float* __restrict__ vm, int vmOff, int vmStride,
    float* __restrict__ Out)
{
  const int b = blockIdx.x >> 6, m = blockIdx.x & 63;
  const int tid = threadIdx.x;
  const int lane = tid & 63, w = tid >> 6;
  float4 tsr[O][2];
#pragma unroll
  for (int o = 0; o < O; ++o) {
    const float4* trow = (const float4*)(T + (((size_t)b * O + o) * NM + m) * (size_t)ND);
    tsr[o][0] = trow[lane];
    tsr[o][1] = (lane < 56) ? trow[64 + lane] : make_float4(0.f, 0.f, 0.f, 0.f);
  }
  float lk[O];
#pragma unroll
  for (int o = 0; o < O; ++o) lk[o] = linK[((size_t)b * NM + m) * O + o] + lb[o];
  const float kmv = km[b * NM + m];
  for (int n = w; n < NVX; n += 4) {
    const float4* vrow = (const float4*)(Val + ((size_t)b * NVX + n) * (size_t)ND);
    float4 v0 = vrow[lane];
    float4 v1 = (lane < 56) ? vrow[64 + lane] : make_float4(0.f, 0.f, 0.f, 0.f);
    float a[3] = {0.f, 0.f, 0.f};
#pragma unroll
    for (int o = 0; o < O; ++o) {
      a[o] = v0.x * tsr[o][0].x + v0.y * tsr[o][0].y + v0.z * tsr[o][0].z + v0.w * tsr[o][0].w
           + v1.x * tsr[o][1].x + v1.y * tsr[o][1].y + v1.z * tsr[o][1].z + v1.w * tsr[o][1].w;
    }
#pragma unroll
    for (int o = 0; o < O; ++o) a[o] = wave_sum(a[o]);
    if (lane == 0) {
      float msk = kmv * vm[b * vmStride + vmOff + n];
      size_t ob = (((size_t)b * NM + m) * NVX + n) * O;
#pragma unroll
      for (int o = 0; o < O; ++o)
        Out[ob + o] = (a[o] + lk[o] + linV[((size_t)b * NVX + n) * O + o]) * msk;
    }
  }
}

// batched small matvec
struct SpCfg { const float* X; const float* W; float* Out; int R; int O; int wStride; int wOff; };
__global__ __launch_bounds__(256) void k_sproj6(
    SpCfg s0, SpCfg s1, SpCfg s2, SpCfg s3, SpCfg s4, SpCfg s5)
{
  int z = blockIdx.y;
  SpCfg c = (z == 0) ? s0 : (z == 1) ? s1 : (z == 2) ? s2 : (z == 3) ? s3 : (z == 4) ? s4 : s5;
  int gid = blockIdx.x * 4 + (threadIdx.x >> 6);
  if (gid >= c.R * c.O) return;
  int lane = threadIdx.x & 63;
  int r = gid / c.O, o = gid - r * c.O;
  const float* x = c.X + (size_t)r * ND;
  const float* wp = c.W + (size_t)o * c.wStride + c.wOff;
  float acc = 0.f;
  for (int d = lane; d < ND; d += 64) acc += x[d] * wp[d];
  acc = wave_sum(acc);
  if (lane == 0) c.Out[gid] = acc;
}

// ---------------- folds ----------------
struct FoldCfg { const float* fw; const float* fb; const float* qw; const float* qb; float* F; int O; };

__global__ __launch_bounds__(256) void k_fold1B(FoldCfg A, FoldCfg Bc)
{
  FoldCfg c = (blockIdx.y == 0) ? A : Bc;
  int O = c.O;
  int gid = blockIdx.x * 4 + (threadIdx.x >> 6);
  int lane = threadIdx.x & 63;
  if (gid >= 3 * ND) return;
  int part = gid / ND, cc0 = gid - part * ND;
  const float* qrow = c.qw + (size_t)(part * ND + cc0) * ND;
  float p0 = 0.f, p1 = 0.f, p2 = 0.f, cc = 0.f;
  for (int d = lane; d < ND; d += 64) {
    float q = qrow[d];
    p0 += c.fw[d * O + 0] * q;
    p1 += c.fw[d * O + 1] * q;
    if (O == 3) p2 += c.fw[d * O + 2] * q;
    cc += c.fb[d] * q;
  }
  p0 = wave_sum(p0); p1 = wave_sum(p1); p2 = wave_sum(p2); cc = wave_sum(cc);
  if (lane == 0) {
    c.F[OF_Pq + part * 1440 + 0 * ND + cc0] = p0;
    c.F[OF_Pq + part * 1440 + 1 * ND + cc0] = p1;
    c.F[OF_Pq + part * 1440 + 2 * ND + cc0] = (O == 3) ? p2 : 0.f;
    c.F[OF_cq + part * ND + cc0] = cc + c.qb[part * ND + cc0];
  }
}

__global__ __launch_bounds__(256) void k_fold2B(FoldCfg A, FoldCfg Bc)
{
  FoldCfg c = (blockIdx.y == 0) ? A : Bc;
  int O = c.O;
  float* F = c.F;
  int gid = blockIdx.x * 4 + (threadIdx.x >> 6);
  int lane = threadIdx.x & 63;
  if (gid < 3 * ND) {
    int part = gid / ND, cc0 = gid - part * ND;
    const float* qrow = c.qw + (size_t)(part * ND + cc0) * ND;
    const float* Pv = F + OF_Pq + 2 * 1440;
    const float* cv = F + OF_cq + 2 * ND;
    float p0 = 0.f, p1 = 0.f, p2 = 0.f, cc = 0.f;
    for (int d = lane; d < ND; d += 64) {
      float q = qrow[d];
      p0 += Pv[0 * ND + d] * q;
      p1 += Pv[1 * ND + d] * q;
      if (O == 3) p2 += Pv[2 * ND + d] * q;
      cc += cv[d] * q;
    }
    p0 = wave_sum(p0); p1 = wave_sum(p1); p2 = wave_sum(p2); cc = wave_sum(cc);
    if (lane == 0) {
      F[OF_Q2 + part * 1440 + 0 * ND + cc0] = p0;
      F[OF_Q2 + part * 1440 + 1 * ND + cc0] = p1;
      F[OF_Q2 + part * 1440 + 2 * ND + cc0] = (O == 3) ? p2 : 0.f;
      F[OF_dq + part * ND + cc0] = cc + c.qb[part * ND + cc0];
    }
  } else if (gid < 3 * ND + 16) {
    int s = gid - 3 * ND;
    const float* Pq = F + OF_Pq;
    const float* Pk = F + OF_Pq + 1440;
    const float* cq = F + OF_cq;
    const float* ck = F + OF_cq + ND;
    float acc = 0.f;
    if (s < 9) {
      int o = s / 3, op = s % 3;
      bool ok = (o < O) && (op < O);
      if (ok) for (int q = lane; q < ND; q += 64) acc += Pq[o * ND + q] * Pk[op * ND + q];
      acc = wave_sum(acc);
      if (lane == 0) F[OF_S + s] = ok ? acc : 0.f;
    } else if (s < 12) {
      int o = s - 9; bool ok = o < O;
      if (ok) for (int q = lane; q < ND; q += 64) acc += Pq[o * ND + q] * ck[q];
      acc = wave_sum(acc);
      if (lane == 0) F[OF_u + o] = ok ? acc : 0.f;
    } else if (s < 15) {
      int o = s - 12; bool ok = o < O;
      if (ok) for (int q = lane; q < ND; q += 64) acc += cq[q] * Pk[o * ND + q];
      acc = wave_sum(acc);
      if (lane == 0) F[OF_r + o] = ok ? acc : 0.f;
    } else {
      for (int q = lane; q < ND; q += 64) acc += cq[q] * ck[q];
      acc = wave_sum(acc);
      if (lane == 0) F[OF_w] = acc;
    }
  }
}

__global__ __launch_bounds__(256) void k_fold3B(FoldCfg A, FoldCfg Bc)
{
  FoldCfg c = (blockIdx.y == 0) ? A : Bc;
  int O = c.O;
  float* F = c.F;
  int s = blockIdx.x * 4 + (threadIdx.x >> 6);
  int lane = threadIdx.x & 63;
  if (s >= 16) return;
  const float* Q2 = F + OF_Q2;
  const float* K2 = F + OF_Q2 + 1440;
  const float* dq = F + OF_dq;
  const float* dk = F + OF_dq + ND;
  float acc = 0.f;
  if (s < 9) {
    int o = s / 3, op = s % 3;
    bool ok = (o < O) && (op < O);
    if (ok) for (int q = lane; q < ND; q += 64) acc += Q2[o * ND + q] * K2[op * ND + q];
    acc = wave_sum(acc);
    if (lane == 0) F[OF_S + 16 + s] = ok ? acc : 0.f;
  } else if (s < 12) {
    int o = s - 9; bool ok = o < O;
    if (ok) for (int q = lane; q < ND; q += 64) acc += Q2[o * ND + q] * dk[q];
    acc = wave_sum(acc);
    if (lane == 0) F[OF_u + 16 + o] = ok ? acc : 0.f;
  } else if (s < 15) {
    int o = s - 12; bool ok = o < O;
    if (ok) for (int q = lane; q < ND; q += 64) acc += dq[q] * K2[o * ND + q];
    acc = wave_sum(acc);
    if (lane == 0) F[OF_r + 16 + o] = ok ? acc : 0.f;
  } else {
    for (int q = lane; q < ND; q += 64) acc += dq[q] * dk[q];
    acc = wave_sum(acc);
    if (lane == 0) F[OF_w + 16] = acc;
  }
}

__global__ void k_multi(const float* __restrict__ a, const float* __restrict__ bb,
                        const float* __restrict__ bc, float* __restrict__ out)
{
  int i = blockIdx.x * blockDim.x + threadIdx.x;
  if (i >= NB * NM * NM * 2) return;
  int c = i & 1;
  int t = i >> 1;
  int n = t % NM; t /= NM;
  int m = t % NM;
  int b = t / NM;
  out[i] = a[((size_t)b * NM + m) * 2 + c] + bb[((size_t)b * NM + n) * 2 + c] + bc[c];
}

template <int O, int NVX>
static void run_rounds(hipStream_t stream,
                       float* keyb, float* valb,
                       u16* kH, u16* kL,
                       const float* kmp, const float* vmp, int vmOff, int vmStride,
                       const u16* WtHp, const u16* WtLp,
                       const float* lwp, const float* lbp,
                       float* fold, float* linK, float* linV,
                       float* tmp, float* Y1, float* Y2, float* outp,
                       const float* typeSrc, const float* keyMaskG, float* km2G, int doType)
{
  dim3 blk(256);
  for (int r = 0; r < 5; ++r) {
    k_tmpM<<<dim3(10, O, NB), blk, 0, stream>>>(kH, kL, WtHp, WtLp, tmp, O,
        typeSrc, keyMaskG, km2G, (r == 0) ? doType : 0);
    if (r < 4) {
      k_bilatt0<O, NVX><<<dim3(NB * NM), blk, 0, stream>>>(
          tmp, valb, linK, linV, lbp, fold, kmp, vmp, vmOff, vmStride, Y1);
      k_att1vupd<O, NVX><<<dim3(NB * NVX), blk, 0, stream>>>(
          Y1, Y2, fold, kmp, vmp, vmOff, vmStride, valb, lwp, linV);
      k_kupd<O, NVX><<<dim3(NB * NM), blk, 0, stream>>>(Y2, fold, keyb, lwp, linK, kH, kL);
    } else {
      k_bilfin<O, NVX><<<dim3(NB * NM), blk, 0, stream>>>(
          tmp, valb, linK, linV, lbp, kmp, vmp, vmOff, vmStride, outp);
    }
  }
}

extern "C" void kernel_launch(void* const* d_in, const int* in_sizes, int n_in,
                              void* d_out, int out_size, void* d_ws, size_t ws_size,
                              hipStream_t stream)
{
  const float* key        = (const float*)d_in[0];
  const float* value      = (const float*)d_in[1];
  const float* key_mask   = (const float*)d_in[2];
  const float* value_mask = (const float*)d_in[3];
  const float* w_kt = (const float*)d_in[4];  const float* b_kt = (const float*)d_in[5];
  const float* w_vt = (const float*)d_in[6];  const float* b_vt = (const float*)d_in[7];
  const float* w_km = (const float*)d_in[8];  const float* b_km = (const float*)d_in[9];
  const float* w_vm = (const float*)d_in[10]; const float* b_vm = (const float*)d_in[11];
  const float* w_ks = (const float*)d_in[12]; const float* b_ks = (const float*)d_in[13];
  const float* w_vs = (const float*)d_in[14]; const float* b_vs = (const float*)d_in[15];
  const float* bt_W = (const float*)d_in[16]; const float* bt_lw = (const float*)d_in[17];
  const float* bt_lb = (const float*)d_in[18];
  const float* bi_W = (const float*)d_in[19]; const float* bi_lw = (const float*)d_in[20];
  const float* bi_lb = (const float*)d_in[21];
  const float* w_ffnt = (const float*)d_in[22]; const float* b_ffnt = (const float*)d_in[23];
  const float* w_ffn  = (const float*)d_in[24]; const float* b_ffn  = (const float*)d_in[25];
  const float* qkvt_w = (const float*)d_in[26]; const float* qkvt_b = (const float*)d_in[27];
  const float* qkv_w  = (const float*)d_in[28]; const float* qkv_b  = (const float*)d_in[29];
  const float* w_cls  = (const float*)d_in[30]; const float* b_cls  = (const float*)d_in[31];

  float* ws = (float*)d_ws;
  size_t off = 0;
  auto alloc = [&](size_t nfloat) { float* p = ws + off; off += (nfloat + 3) & ~(size_t)3; return p; };

  float* kt_t   = alloc((size_t)NB * NM * ND);
  float* vt_t   = alloc((size_t)NB * NNV * ND);
  float* kt_s   = alloc((size_t)NB * NM * ND);
  float* vt_s   = alloc((size_t)NB * NM * ND);
  float* tmp    = alloc((size_t)NB * 3 * NM * ND);
  float* Y1     = alloc((size_t)NB * NM * NNV * 3);
  float* Y2     = alloc((size_t)NB * NM * NNV * 3);
  float* linK_t = alloc((size_t)NB * NM * 3);
  float* linV_t = alloc((size_t)NB * NNV * 3);
  float* linK_s = alloc((size_t)NB * NM * 3);
  float* linV_s = alloc((size_t)NB * NM * 3);
  float* fold_t = alloc(FOLD_SZ);
  float* fold_s = alloc(FOLD_SZ);
  float* km2    = alloc((size_t)NB * NM);
  float* a2     = alloc((size_t)NB * NM * 2);
  float* b2     = alloc((size_t)NB * NM * 2);
  u16* WtH = (u16*)alloc((size_t)5 * ND * ND / 2);
  u16* WtL = (u16*)alloc((size_t)5 * ND * ND / 2);
  u16* keyH_t = (u16*)alloc((size_t)NB * NM * ND / 2);
  u16* keyL_t = (u16*)alloc((size_t)NB * NM * ND / 2);
  u16* keyH_s = (u16*)alloc((size_t)NB * NM * ND / 2);
  u16* keyL_s = (u16*)alloc((size_t)NB * NM * ND / 2);
  (void)ws_size; (void)in_sizes; (void)n_in; (void)out_size;

  float* kmf = tmp;                               // projections done before rounds use tmp
  float* vmf = tmp + (size_t)NB * NM * ND;

  float* out_type   = (float*)d_out;
  float* out_multi  = out_type + (size_t)NB * NM * NNV * 3;
  float* out_single = out_multi + (size_t)NB * NM * NM * 2;

  dim3 blk(256);

  // ---- W^T bf16 planes for the 5 biaffine matrices (one-time) ----
  k_cvtT<<<dim3(15, 15, 5), blk, 0, stream>>>(bt_W, bi_W, WtH, WtL);

  // ---- all 6 big projections, one MFMA launch (key configs also write bf16 planes) ----
  Proj6 P;
  P.c[0] = { key,   w_kt, b_kt, kt_t, keyH_t, keyL_t, NB * NM,  0, NM,  NM * NH };
  P.c[1] = { value, w_vt, b_vt, vt_t, nullptr, nullptr, NB * NNV, 0, NNV, NNV * NH };
  P.c[2] = { key,   w_ks, b_ks, kt_s, keyH_s, keyL_s, NB * NM,  0, NM,  NM * NH };
  P.c[3] = { value, w_vs, b_vs, vt_s, nullptr, nullptr, NB * NM,  1, NM,  NNV * NH };
  P.c[4] = { key,   w_km, b_km, kmf,  nullptr, nullptr, NB * NM,  0, NM,  NM * NH };
  P.c[5] = { value, w_vm, b_vm, vmf,  nullptr, nullptr, NB * NM,  1, NM,  NNV * NH };
  k_projM<<<dim3(193 * 10), blk, 0, stream>>>(P, NH);

  // ---- folds for both paths (batched) ----
  FoldCfg ft = { w_ffnt, b_ffnt, qkvt_w, qkvt_b, fold_t, 3 };
  FoldCfg fs = { w_ffn,  b_ffn,  qkv_w,  qkv_b,  fold_s, 2 };
  k_fold1B<<<dim3(360, 2), blk, 0, stream>>>(ft, fs);
  k_fold2B<<<dim3(364, 2), blk, 0, stream>>>(ft, fs);
  k_fold3B<<<dim3(4, 2), blk, 0, stream>>>(ft, fs);

  // ---- all small matvecs, one launch ----
  SpCfg s0 = { kt_t, bt_lw, linK_t, NB * NM,  3, 2 * ND, 0 };
  SpCfg s1 = { vt_t, bt_lw, linV_t, NB * NNV, 3, 2 * ND, ND };
  SpCfg s2 = { kt_s, bi_lw, linK_s, NB * NM,  2, 2 * ND, 0 };
  SpCfg s3 = { vt_s, bi_lw, linV_s, NB * NM,  2, 2 * ND, ND };
  SpCfg s4 = { kmf,  w_cls, a2,     NB * NM,  2, 2 * ND, 0 };
  SpCfg s5 = { vmf,  w_cls, b2,     NB * NM,  2, 2 * ND, ND };
  k_sproj6<<<dim3((NB * NNV * 3 + 3) / 4, 6), blk, 0, stream>>>(s0, s1, s2, s3, s4, s5);

  // multi logits (independent of rounds)
  k_multi<<<dim3((NB * NM * NM * 2 + 255) / 256), blk, 0, stream>>>(a2, b2, b_cls, out_multi);

  // ---- type path rounds ----
  run_rounds<3, NNV>(stream, kt_t, vt_t, keyH_t, keyL_t, key_mask, value_mask, 0, NNV,
                     WtH, WtL, bt_lw, bt_lb, fold_t, linK_t, linV_t,
                     tmp, Y1, Y2, out_type, nullptr, nullptr, nullptr, 0);

  // ---- single path rounds (first tmpM computes km2 from out_type in its epilogue) ----
  run_rounds<2, NM>(stream, kt_s, vt_s, keyH_s, keyL_s, km2, value_mask, 1, NNV,
                    WtH + (size_t)3 * ND * ND, WtL + (size_t)3 * ND * ND,
                    bi_lw, bi_lb, fold_s, linK_s, linV_s,
                    tmp, Y1, Y2, out_single, out_type, key_mask, km2, 1);
}

// Round 13
// 1071.602 us; speedup vs baseline: 1.0015x; 1.0015x over previous
//
#include <hip/hip_runtime.h>
#include <math.h>

// ---------------- problem constants ----------------
constexpr int NB = 32;    // B
constexpr int NM = 64;    // M
constexpr int NNV = 65;   // NV
constexpr int NH = 960;   // H
constexpr int ND = 480;   // D
constexpr float ATT_SCALE = 0.045643546458763842f;  // D^-0.5

constexpr int OF_Pq = 0;
constexpr int OF_cq = 4320;
constexpr int OF_Q2 = 5760;
constexpr int OF_V2 = OF_Q2 + 2*1440;
constexpr int OF_dq = 10080;
constexpr int OF_dv = OF_dq + 2*480;
constexpr int OF_S  = 11520;
constexpr int OF_u  = 11529;
constexpr int OF_r  = 11532;
constexpr int OF_w  = 11535;
constexpr int FOLD_SZ = 11552;

typedef unsigned short u16;
typedef float f32x4 __attribute__((ext_vector_type(4)));
typedef short s16x8 __attribute__((ext_vector_type(8)));

__device__ __forceinline__ float wave_sum(float v) {
#pragma unroll
  for (int d = 32; d; d >>= 1) v += __shfl_xor(v, d);
  return v;
}

__device__ __forceinline__ void split_bf16(float x, short& hi, short& lo) {
  union { float f; unsigned u; } a; a.f = x;
  unsigned uh = a.u + 0x7fffu + ((a.u >> 16) & 1u);
  hi = (short)(uh >> 16);
  union { unsigned u; float f; } b; b.u = ((unsigned)(unsigned short)hi) << 16;
  union { float f; unsigned u; } c; c.f = x - b.f;
  unsigned ul = c.u + 0x7fffu + ((c.u >> 16) & 1u);
  lo = (short)(ul >> 16);
}

// ---------------- combined converter: z<5 transpose W planes; z>=5 elementwise jobs ----------------
struct CvtJob { const float* s; u16* h; u16* l; int n4; };
struct CvtAll { CvtJob j[8]; };

__global__ __launch_bounds__(256) void k_cvtAll(
    const float* __restrict__ btW, const float* __restrict__ biW,
    u16* __restrict__ wtHi, u16* __restrict__ wtLo, CvtAll C)
{
  const int z = blockIdx.z;
  if (z < 5) {
    __shared__ float s[32][33];
    const float* src = (z < 3) ? (btW + (size_t)z * ND * ND) : (biW + (size_t)(z - 3) * ND * ND);
    u16* dh = wtHi + (size_t)z * ND * ND;
    u16* dl = wtLo + (size_t)z * ND * ND;
    const int k0 = blockIdx.y * 32, n0 = blockIdx.x * 32;
    const int tx = threadIdx.x & 31, ty = threadIdx.x >> 5;
#pragma unroll
    for (int q = 0; q < 4; ++q)
      s[ty + q * 8][tx] = src[(size_t)(k0 + ty + q * 8) * ND + n0 + tx];
    __syncthreads();
#pragma unroll
    for (int q = 0; q < 4; ++q) {
      float v = s[tx][ty + q * 8];
      short h, l; split_bf16(v, h, l);
      size_t di = (size_t)(n0 + ty + q * 8) * ND + k0 + tx;
      dh[di] = (u16)h; dl[di] = (u16)l;
    }
  } else {
    CvtJob jb = C.j[z - 5];
    int idx0 = (blockIdx.y * 15 + blockIdx.x) * 256 + threadIdx.x;
    for (int i = idx0; i < jb.n4; i += 225 * 256) {
      float4 v = ((const float4*)jb.s)[i];
      short h0, l0, h1, l1, h2, l2, h3, l3;
      split_bf16(v.x, h0, l0); split_bf16(v.y, h1, l1);
      split_bf16(v.z, h2, l2); split_bf16(v.w, h3, l3);
      ushort4 hv, lv;
      hv.x = (u16)h0; hv.y = (u16)h1; hv.z = (u16)h2; hv.w = (u16)h3;
      lv.x = (u16)l0; lv.y = (u16)l1; lv.z = (u16)l2; lv.w = (u16)l3;
      ((ushort4*)jb.h)[i] = hv;
      ((ushort4*)jb.l)[i] = lv;
    }
  }
}

// ---------------- MFMA projection GEMM: fully plane-based A and B ----------------
struct ProjCfg {
  const u16* XH; const u16* XL; const u16* WH; const u16* WL;
  const float* bias; float* C;
  u16* pH; u16* pL;
  int R; int x0; int rpb; int xbs;
};
struct Proj6 { ProjCfg c[6]; };

constexpr int KP = 40;   // padded k stride (ushorts)

__global__ __launch_bounds__(256) void k_projM(Proj6 P, int K)
{
  __shared__ u16 As_hi[64][KP], As_lo[64][KP];
  __shared__ u16 Bs_hi[48][KP], Bs_lo[48][KP];
  int p = blockIdx.x, total = gridDim.x;
  int q = total >> 3, r = total & 7;
  int xk = p & 7, idx = p >> 3;
  int lgc = (xk < r) ? (xk * (q + 1) + idx) : (r * (q + 1) + (xk - r) * q + idx);
  int mp = lgc / 10, nx = lgc - mp * 10;
  ProjCfg cfg; int my;
  if      (mp < 32)  { cfg = P.c[0]; my = mp; }
  else if (mp < 65)  { cfg = P.c[1]; my = mp - 32; }
  else if (mp < 97)  { cfg = P.c[2]; my = mp - 65; }
  else if (mp < 129) { cfg = P.c[3]; my = mp - 97; }
  else if (mp < 161) { cfg = P.c[4]; my = mp - 129; }
  else               { cfg = P.c[5]; my = mp - 161; }
  const int m0 = my * 64, n0 = nx * 48;
  const int tid = threadIdx.x;
  const int l6 = tid & 63, w = tid >> 6;
  const int lr = tid >> 2, kc = (tid & 3) * 8;
  size_t aoff = 0; bool aok = false;
  {
    int rr = m0 + lr;
    if (rr < cfg.R) {
      int b = rr / cfg.rpb, r2 = rr - b * cfg.rpb;
      aoff = (size_t)b * cfg.xbs + (size_t)(cfg.x0 + r2) * K;
      aok = true;
    }
  }
  const bool bok2 = lr < 48;
  const size_t boff = (size_t)(n0 + (bok2 ? lr : 0)) * K;
  const int fr = l6 & 15, fk = (l6 >> 4) * 8;
  const s16x8 zf = {0, 0, 0, 0, 0, 0, 0, 0};
  f32x4 acc0 = {0.f, 0.f, 0.f, 0.f}, acc1 = acc0, acc2 = acc0;
  for (int k0 = 0; k0 < K; k0 += 32) {
    *(s16x8*)&As_hi[lr][kc] = aok ? *(const s16x8*)(cfg.XH + aoff + k0 + kc) : zf;
    *(s16x8*)&As_lo[lr][kc] = aok ? *(const s16x8*)(cfg.XL + aoff + k0 + kc) : zf;
    if (bok2) {
      *(s16x8*)&Bs_hi[lr][kc] = *(const s16x8*)(cfg.WH + boff + k0 + kc);
      *(s16x8*)&Bs_lo[lr][kc] = *(const s16x8*)(cfg.WL + boff + k0 + kc);
    }
    __syncthreads();
    s16x8 ah = *(const s16x8*)&As_hi[16 * w + fr][fk];
    s16x8 al = *(const s16x8*)&As_lo[16 * w + fr][fk];
    {
      s16x8 bh = *(const s16x8*)&Bs_hi[fr][fk];
      s16x8 bl = *(const s16x8*)&Bs_lo[fr][fk];
      acc0 = __builtin_amdgcn_mfma_f32_16x16x32_bf16(ah, bh, acc0, 0, 0, 0);
      acc0 = __builtin_amdgcn_mfma_f32_16x16x32_bf16(ah, bl, acc0, 0, 0, 0);
      acc0 = __builtin_amdgcn_mfma_f32_16x16x32_bf16(al, bh, acc0, 0, 0, 0);
    }
    {
      s16x8 bh = *(const s16x8*)&Bs_hi[16 + fr][fk];
      s16x8 bl = *(const s16x8*)&Bs_lo[16 + fr][fk];
      acc1 = __builtin_amdgcn_mfma_f32_16x16x32_bf16(ah, bh, acc1, 0, 0, 0);
      acc1 = __builtin_amdgcn_mfma_f32_16x16x32_bf16(ah, bl, acc1, 0, 0, 0);
      acc1 = __builtin_amdgcn_mfma_f32_16x16x32_bf16(al, bh, acc1, 0, 0, 0);
    }
    {
      s16x8 bh = *(const s16x8*)&Bs_hi[32 + fr][fk];
      s16x8 bl = *(const s16x8*)&Bs_lo[32 + fr][fk];
      acc2 = __builtin_amdgcn_mfma_f32_16x16x32_bf16(ah, bh, acc2, 0, 0, 0);
      acc2 = __builtin_amdgcn_mfma_f32_16x16x32_bf16(ah, bl, acc2, 0, 0, 0);
      acc2 = __builtin_amdgcn_mfma_f32_16x16x32_bf16(al, bh, acc2, 0, 0, 0);
    }
    __syncthreads();
  }
#pragma unroll
  for (int c = 0; c < 3; ++c) {
    f32x4 av = (c == 0) ? acc0 : (c == 1) ? acc1 : acc2;
    int n = n0 + 16 * c + fr;
    float bv = cfg.bias[n];
#pragma unroll
    for (int g = 0; g < 4; ++g) {
      int rr = m0 + 16 * w + (l6 >> 4) * 4 + g;
      if (rr < cfg.R) {
        float v = av[g] + bv;
        size_t di = (size_t)rr * ND + n;
        cfg.C[di] = v;
        if (cfg.pH) {
          short h, lo2; split_bf16(v, h, lo2);
          cfg.pH[di] = (u16)h; cfg.pL[di] = (u16)lo2;
        }
      }
    }
  }
}

// ---------------- MFMA tmp GEMM: plane-based A (key u16) and B (W^T u16) ----------------
__global__ __launch_bounds__(256) void k_tmpM(
    const u16* __restrict__ KH, const u16* __restrict__ KL,
    const u16* __restrict__ WtH, const u16* __restrict__ WtL,
    float* __restrict__ T, int O,
    const float* __restrict__ typeSrc, const float* __restrict__ keyMask,
    float* __restrict__ km2, int doType)
{
  __shared__ u16 As_hi[64][KP], As_lo[64][KP];
  __shared__ u16 Bs_hi[48][KP], Bs_lo[48][KP];
  const int n0 = blockIdx.x * 48;
  const int o = blockIdx.y, b = blockIdx.z;
  const int tid = threadIdx.x;
  if (doType && blockIdx.x == 0 && blockIdx.y == 0 && tid < NM) {
    const float* p = typeSrc + ((size_t)(b * NM + tid)) * NNV * 3;
    float l0 = p[0], l1 = p[1], l2 = p[2];
    int arg = 0; float best = l0;
    if (l1 > best) { best = l1; arg = 1; }
    if (l2 > best) { arg = 2; }
    km2[b * NM + tid] = (keyMask[b * NM + tid] != 0.f && arg == 1) ? 1.f : 0.f;
  }
  const int l6 = tid & 63, w = tid >> 6;
  const int lr = tid >> 2, kc = (tid & 3) * 8;
  const size_t aoff = ((size_t)b * NM + lr) * ND;
  const bool bok = lr < 48;
  const size_t boff = ((size_t)o * ND + n0 + (bok ? lr : 0)) * ND;
  const int fr = l6 & 15, fk = (l6 >> 4) * 8;
  f32x4 acc0 = {0.f, 0.f, 0.f, 0.f}, acc1 = acc0, acc2 = acc0;
  for (int k0 = 0; k0 < ND; k0 += 32) {
    *(s16x8*)&As_hi[lr][kc] = *(const s16x8*)(KH + aoff + k0 + kc);
    *(s16x8*)&As_lo[lr][kc] = *(const s16x8*)(KL + aoff + k0 + kc);
    if (bok) {
      *(s16x8*)&Bs_hi[lr][kc] = *(const s16x8*)(WtH + boff + k0 + kc);
      *(s16x8*)&Bs_lo[lr][kc] = *(const s16x8*)(WtL + boff + k0 + kc);
    }
    __syncthreads();
    s16x8 ah = *(const s16x8*)&As_hi[16 * w + fr][fk];
    s16x8 al = *(const s16x8*)&As_lo[16 * w + fr][fk];
    {
      s16x8 bh = *(const s16x8*)&Bs_hi[fr][fk];
      s16x8 bl = *(const s16x8*)&Bs_lo[fr][fk];
      acc0 = __builtin_amdgcn_mfma_f32_16x16x32_bf16(ah, bh, acc0, 0, 0, 0);
      acc0 = __builtin_amdgcn_mfma_f32_16x16x32_bf16(ah, bl, acc0, 0, 0, 0);
      acc0 = __builtin_amdgcn_mfma_f32_16x16x32_bf16(al, bh, acc0, 0, 0, 0);
    }
    {
      s16x8 bh = *(const s16x8*)&Bs_hi[16 + fr][fk];
      s16x8 bl = *(const s16x8*)&Bs_lo[16 + fr][fk];
      acc1 = __builtin_amdgcn_mfma_f32_16x16x32_bf16(ah, bh, acc1, 0, 0, 0);
      acc1 = __builtin_amdgcn_mfma_f32_16x16x32_bf16(ah, bl, acc1, 0, 0, 0);
      acc1 = __builtin_amdgcn_mfma_f32_16x16x32_bf16(al, bh, acc1, 0, 0, 0);
    }
    {
      s16x8 bh = *(const s16x8*)&Bs_hi[32 + fr][fk];
      s16x8 bl = *(const s16x8*)&Bs_lo[32 + fr][fk];
      acc2 = __builtin_amdgcn_mfma_f32_16x16x32_bf16(ah, bh, acc2, 0, 0, 0);
      acc2 = __builtin_amdgcn_mfma_f32_16x16x32_bf16(ah, bl, acc2, 0, 0, 0);
      acc2 = __builtin_amdgcn_mfma_f32_16x16x32_bf16(al, bh, acc2, 0, 0, 0);
    }
    __syncthreads();
  }
  float* C = T + ((size_t)(b * O + o) * NM) * ND;
#pragma unroll
  for (int c = 0; c < 3; ++c) {
    f32x4 av = (c == 0) ? acc0 : (c == 1) ? acc1 : acc2;
    int n = n0 + 16 * c + fr;
#pragma unroll
    for (int g = 0; g < 4; ++g) {
      int rr = 16 * w + (l6 >> 4) * 4 + g;
      C[(size_t)rr * ND + n] = av[g];
    }
  }
}

// fused bilinear + attention(MODE0) per (b,m) with parallel softmax
template <int O, int NVX>
__global__ __launch_bounds__(256) void k_bilatt0(
    const float* __restrict__ T, const float* __restrict__ Val,
    const float* __restrict__ linK, const float* __restrict__ linV,
    const float* __restrict__ lb, const float* __restrict__ F,
    const float* __restrict__ km, const float* __restrict__ vm,
    int vmOff, int vmStride, float* __restrict__ Y1)
{
  __shared__ float Ls[NVX][3];
  __shared__ float STs[NVX][3];
  __shared__ float hs[NVX], gs[NVX], mkj[NVX];
  __shared__ float Pm[NVX][66];
  __shared__ float rmx[NVX][3];
  __shared__ float rsum[NVX][3];
  __shared__ float ry[NVX][3][3];
  __shared__ float lvs[NVX][3];
  const int b = blockIdx.x >> 6, m = blockIdx.x & 63;
  const int tid = threadIdx.x;
  const int lane = tid & 63, w = tid >> 6;

  for (int j = tid; j < NVX; j += 256) {
    mkj[j] = vm[b * vmStride + vmOff + j];
#pragma unroll
    for (int o = 0; o < O; ++o) lvs[j][o] = linV[((size_t)b * NVX + j) * O + o];
  }
  float4 tsr[O][2];
#pragma unroll
  for (int o = 0; o < O; ++o) {
    const float4* trow = (const float4*)(T + (((size_t)b * O + o) * NM + m) * (size_t)ND);
    tsr[o][0] = trow[lane];
    tsr[o][1] = (lane < 56) ? trow[64 + lane] : make_float4(0.f, 0.f, 0.f, 0.f);
  }
  float lk[O];
#pragma unroll
  for (int o = 0; o < O; ++o) lk[o] = linK[((size_t)b * NM + m) * O + o] + lb[o];
  const float gm = km[b * NM + m];
  const bool gz = (gm == 0.f);

  for (int n = w; n < NVX; n += 4) {
    const float4* vrow = (const float4*)(Val + ((size_t)b * NVX + n) * (size_t)ND);
    float4 v0 = vrow[lane];
    float4 v1 = (lane < 56) ? vrow[64 + lane] : make_float4(0.f, 0.f, 0.f, 0.f);
    float a[3] = {0.f, 0.f, 0.f};
#pragma unroll
    for (int o = 0; o < O; ++o) {
      a[o] = v0.x * tsr[o][0].x + v0.y * tsr[o][0].y + v0.z * tsr[o][0].z + v0.w * tsr[o][0].w
           + v1.x * tsr[o][1].x + v1.y * tsr[o][1].y + v1.z * tsr[o][1].z + v1.w * tsr[o][1].w;
    }
#pragma unroll
    for (int o = 0; o < O; ++o) a[o] = wave_sum(a[o]);
    if (lane == 0) {
#pragma unroll
      for (int o = 0; o < O; ++o) Ls[n][o] = a[o] + lk[o] + lvs[n][o];
      if (O == 2) Ls[n][2] = 0.f;
    }
  }
  __syncthreads();
  const float* Sm = F + OF_S;
  const float u0 = F[OF_u], u1 = F[OF_u + 1], u2 = F[OF_u + 2];
  const float r0 = F[OF_r], r1 = F[OF_r + 1], r2 = F[OF_r + 2];
  const float wc = F[OF_w];
  if (tid < NVX) {
    int j = tid;
    float t0 = Ls[j][0], t1 = Ls[j][1], t2 = Ls[j][2];
    STs[j][0] = t0 * Sm[0] + t1 * Sm[3] + t2 * Sm[6];
    STs[j][1] = t0 * Sm[1] + t1 * Sm[4] + t2 * Sm[7];
    STs[j][2] = t0 * Sm[2] + t1 * Sm[5] + t2 * Sm[8];
    hs[j] = t0 * u0 + t1 * u1 + t2 * u2;
    gs[j] = t0 * r0 + t1 * r1 + t2 * r2;
  }
  __syncthreads();
  const bool act = tid < NVX * 3;
  int i = 0, qq = 0, jlo = 0, jhi = 0;
  float st0 = 0, st1 = 0, st2 = 0, hi = 0;
  bool rowz = true;
  if (act) {
    i = tid / 3; qq = tid - i * 3;
    jlo = qq * 22; jhi = (jlo + 22 < NVX) ? jlo + 22 : NVX;
    st0 = STs[i][0]; st1 = STs[i][1]; st2 = STs[i][2]; hi = hs[i];
    rowz = gz || (mkj[i] == 0.f);
    float mx = -3.0e38f;
    for (int j = jlo; j < jhi; ++j) {
      float s = st0 * Ls[j][0] + st1 * Ls[j][1] + hi + gs[j] + wc;
      if (O == 3) s += st2 * Ls[j][2];
      s = (rowz || mkj[j] == 0.f) ? -10000.f : ATT_SCALE * s;
      Pm[i][j] = s;
      mx = fmaxf(mx, s);
    }
    rmx[i][qq] = mx;
  }
  __syncthreads();
  if (act) {
    float mx = fmaxf(fmaxf(rmx[i][0], rmx[i][1]), rmx[i][2]);
    float sum = 0.f, y0 = 0.f, y1 = 0.f, y2 = 0.f;
    for (int j = jlo; j < jhi; ++j) {
      float pp = __expf(Pm[i][j] - mx);
      sum += pp; y0 += pp * Ls[j][0]; y1 += pp * Ls[j][1];
      if (O == 3) y2 += pp * Ls[j][2];
    }
    rsum[i][qq] = sum; ry[i][qq][0] = y0; ry[i][qq][1] = y1; ry[i][qq][2] = y2;
  }
  __syncthreads();
  if (tid < NVX) {
    int ii = tid;
    float sum = rsum[ii][0] + rsum[ii][1] + rsum[ii][2];
    float y0 = ry[ii][0][0] + ry[ii][1][0] + ry[ii][2][0];
    float y1 = ry[ii][0][1] + ry[ii][1][1] + ry[ii][2][1];
    float y2 = ry[ii][0][2] + ry[ii][1][2] + ry[ii][2][2];
    float inv = 1.f / sum;
    size_t ob = (((size_t)b * NM + m) * NVX + ii) * O;
    Y1[ob + 0] = y0 * inv;
    Y1[ob + 1] = y1 * inv;
    if (O == 3) Y1[ob + 2] = y2 * inv;
  }
}

// fused attention(MODE1) + value-update + linV per (b,n), parallel softmax
template <int O, int NVX>
__global__ __launch_bounds__(256) void k_att1vupd(
    const float* __restrict__ Y1, float* __restrict__ Y2,
    const float* __restrict__ F,
    const float* __restrict__ km, const float* __restrict__ vm,
    int vmOff, int vmStride,
    float* __restrict__ valb, const float* __restrict__ lw,
    float* __restrict__ linV)
{
  __shared__ float Ys1[NM][3];
  __shared__ float STs[NM][3];
  __shared__ float hs[NM], gs[NM], mkm[NM];
  __shared__ float Pm[NM][66];
  __shared__ float rmx[NM][3];
  __shared__ float rsum[NM][3];
  __shared__ float ry[NM][3][3];
  __shared__ float Ys2[NM][3];
  __shared__ float vrow[ND];
  const int b = blockIdx.x / NVX, n = blockIdx.x - b * NVX;
  const int tid = threadIdx.x;
  for (int u = tid; u < NM * O; u += 256) {
    int mm = u % NM, o = u / NM;
    Ys1[mm][o] = Y1[(((size_t)b * NM + mm) * NVX + n) * O + o];
  }
  if (tid < NM) {
    mkm[tid] = km[b * NM + tid];
    if (O == 2) Ys1[tid][2] = 0.f;
  }
  const float gm = vm[b * vmStride + vmOff + n];
  const bool gz = (gm == 0.f);
  __syncthreads();
  const float* Sm = F + OF_S + 16;
  const float u0 = F[OF_u + 16], u1 = F[OF_u + 17], u2 = F[OF_u + 18];
  const float r0 = F[OF_r + 16], r1 = F[OF_r + 17], r2 = F[OF_r + 18];
  const float wc = F[OF_w + 16];
  if (tid < NM) {
    int j = tid;
    float t0 = Ys1[j][0], t1 = Ys1[j][1], t2 = Ys1[j][2];
    STs[j][0] = t0 * Sm[0] + t1 * Sm[3] + t2 * Sm[6];
    STs[j][1] = t0 * Sm[1] + t1 * Sm[4] + t2 * Sm[7];
    STs[j][2] = t0 * Sm[2] + t1 * Sm[5] + t2 * Sm[8];
    hs[j] = t0 * u0 + t1 * u1 + t2 * u2;
    gs[j] = t0 * r0 + t1 * r1 + t2 * r2;
  }
  __syncthreads();
  const bool act = tid < NM * 3;
  int i = 0, qq = 0, jlo = 0, jhi = 0;
  float st0 = 0, st1 = 0, st2 = 0, hi = 0;
  bool rowz = true;
  if (act) {
    i = tid / 3; qq = tid - i * 3;
    jlo = qq * 22; jhi = (jlo + 22 < NM) ? jlo + 22 : NM;
    st0 = STs[i][0]; st1 = STs[i][1]; st2 = STs[i][2]; hi = hs[i];
    rowz = gz || (mkm[i] == 0.f);
    float mx = -3.0e38f;
    for (int j = jlo; j < jhi; ++j) {
      float s = st0 * Ys1[j][0] + st1 * Ys1[j][1] + hi + gs[j] + wc;
      if (O == 3) s += st2 * Ys1[j][2];
      s = (rowz || mkm[j] == 0.f) ? -10000.f : ATT_SCALE * s;
      Pm[i][j] = s;
      mx = fmaxf(mx, s);
    }
    rmx[i][qq] = mx;
  }
  __syncthreads();
  if (act) {
    float mx = fmaxf(fmaxf(rmx[i][0], rmx[i][1]), rmx[i][2]);
    float sum = 0.f, y0 = 0.f, y1 = 0.f, y2 = 0.f;
    for (int j = jlo; j < jhi; ++j) {
      float pp = __expf(Pm[i][j] - mx);
      sum += pp; y0 += pp * Ys1[j][0]; y1 += pp * Ys1[j][1];
      if (O == 3) y2 += pp * Ys1[j][2];
    }
    rsum[i][qq] = sum; ry[i][qq][0] = y0; ry[i][qq][1] = y1; ry[i][qq][2] = y2;
  }
  __syncthreads();
  if (tid < NM) {
    int ii = tid;
    float sum = rsum[ii][0] + rsum[ii][1] + rsum[ii][2];
    float y0 = ry[ii][0][0] + ry[ii][1][0] + ry[ii][2][0];
    float y1 = ry[ii][0][1] + ry[ii][1][1] + ry[ii][2][1];
    float y2 = ry[ii][0][2] + ry[ii][1][2] + ry[ii][2][2];
    float inv = 1.f / sum;
    y0 *= inv; y1 *= inv; y2 *= inv;
    size_t ob = (((size_t)b * NVX + n) * NM + ii) * O;
    Y2[ob + 0] = y0; Y2[ob + 1] = y1;
    if (O == 3) Y2[ob + 2] = y2;
    Ys2[ii][0] = y0; Ys2[ii][1] = y1; Ys2[ii][2] = (O == 3) ? y2 : 0.f;
  }
  __syncthreads();
  const float* V2 = F + OF_V2;
  const float* dv = F + OF_dv;
  for (int d = tid; d < ND; d += 256) {
    float v0 = V2[d], v1 = V2[ND + d], v2 = (O == 3) ? V2[2 * ND + d] : 0.f;
    float mx = -3.0e38f;
    for (int j = 0; j < NM; ++j) {
      float s = Ys2[j][0] * v0 + Ys2[j][1] * v1;
      if (O == 3) s += Ys2[j][2] * v2;
      mx = fmaxf(mx, s);
    }
    size_t di = ((size_t)b * NVX + n) * ND + d;
    float nv = valb[di] + mx + dv[d];
    valb[di] = nv;
    vrow[d] = nv;
  }
  __syncthreads();
  const int wv = tid >> 6, lane = tid & 63;
  if (wv < O) {
    float acc = 0.f;
    for (int d = lane; d < ND; d += 64) acc += vrow[d] * lw[(size_t)wv * 2 * ND + ND + d];
    acc = wave_sum(acc);
    if (lane == 0) linV[((size_t)b * NVX + n) * O + wv] = acc;
  }
}

// fused key-update + linK + key plane refresh per (b,m)
template <int O, int NVX>
__global__ __launch_bounds__(256) void k_kupd(
    const float* __restrict__ Y2, const float* __restrict__ F,
    float* __restrict__ keyb, const float* __restrict__ lw,
    float* __restrict__ linK, u16* __restrict__ kH, u16* __restrict__ kL)
{
  __shared__ float Ys[NVX][3];
  __shared__ float krow[ND];
  const int b = blockIdx.x >> 6, m = blockIdx.x & 63;
  const int tid = threadIdx.x;
  for (int u = tid; u < NVX * O; u += 256) {
    int j = u % NVX, o = u / NVX;
    Ys[j][o] = Y2[(((size_t)b * NVX + j) * NM + m) * O + o];
  }
  __syncthreads();
  const float* V2 = F + OF_V2;
  const float* dv = F + OF_dv;
  for (int d = tid; d < ND; d += 256) {
    float v0 = V2[d], v1 = V2[ND + d], v2 = (O == 3) ? V2[2 * ND + d] : 0.f;
    float mx = -3.0e38f;
    for (int j = 0; j < NVX; ++j) {
      float s = Ys[j][0] * v0 + Ys[j][1] * v1;
      if (O == 3) s += Ys[j][2] * v2;
      mx = fmaxf(mx, s);
    }
    size_t di = ((size_t)b * NM + m) * ND + d;
    float nv = keyb[di] + mx + dv[d];
    keyb[di] = nv;
    krow[d] = nv;
    short h, l; split_bf16(nv, h, l);
    kH[di] = (u16)h; kL[di] = (u16)l;
  }
  __syncthreads();
  const int wv = tid >> 6, lane = tid & 63;
  if (wv < O) {
    float acc = 0.f;
    for (int d = lane; d < ND; d += 64) acc += krow[d] * lw[(size_t)wv * 2 * ND + d];
    acc = wave_sum(acc);
    if (lane == 0) linK[((size_t)b * NM + m) * O + wv] = acc;
  }
}

// final bilinear with mask, register-ts + global Val
template <int O, int NVX>
__global__ __launch_bounds__(256) void k_bilfin(
    const float* __restrict__ T, const float* __restrict__ Val,
    const float* __restrict__ linK, const float* __restrict__ linV,
    const float* __restrict__ lb, const float* __restrict__ km,
    const float* __restrict__ vm, int vmOff, int vmStride,
    float* __restrict__ Out)
{
  const int b = blockIdx.x >> 6, m = blockIdx.x & 63;
  const int tid = threadIdx.x;
  const int lane = tid & 63, w = tid >> 6;
  float4 tsr[O][2];
#pragma unroll
  for (int o = 0; o < O; ++o) {
    const float4* trow = (const float4*)(T + (((size_t)b * O + o) * NM + m) * (size_t)ND);
    tsr[o][0] = trow[lane];
    tsr[o][1] = (lane < 56) ? trow[64 + lane] : make_float4(0.f, 0.f, 0.f, 0.f);
  }
  float lk[O];
#pragma unroll
  for (int o = 0; o < O; ++o) lk[o] = linK[((size_t)b * NM + m) * O + o] + lb[o];
  const float kmv = km[b * NM + m];
  for (int n = w; n < NVX; n += 4) {
    const float4* vrow = (const float4*)(Val + ((size_t)b * NVX + n) * (size_t)ND);
    float4 v0 = vrow[lane];
    float4 v1 = (lane < 56) ? vrow[64 + lane] : make_float4(0.f, 0.f, 0.f, 0.f);
    float a[3] = {0.f, 0.f, 0.f};
#pragma unroll
    for (int o = 0; o < O; ++o) {
      a[o] = v0.x * tsr[o][0].x + v0.y * tsr[o][0].y + v0.z * tsr[o][0].z + v0.w * tsr[o][0].w
           + v1.x * tsr[o][1].x + v1.y * tsr[o][1].y + v1.z * tsr[o][1].z + v1.w * tsr[o][1].w;
    }
#pragma unroll
    for (int o = 0; o < O; ++o) a[o] = wave_sum(a[o]);
    if (lane == 0) {
      float msk = kmv * vm[b * vmStride + vmOff + n];
      size_t ob = (((size_t)b * NM + m) * NVX + n) * O;
#pragma unroll
      for (int o = 0; o < O; ++o)
        Out[ob + o] = (a[o] + lk[o] + linV[((size_t)b * NVX + n) * O + o]) * msk;
    }
  }
}

// batched small matvec
struct SpCfg { const float* X; const float* W; float* Out; int R; int O; int wStride; int wOff; };
__global__ __launch_bounds__(256) void k_sproj6(
    SpCfg s0, SpCfg s1, SpCfg s2, SpCfg s3, SpCfg s4, SpCfg s5)
{
  int z = blockIdx.y;
  SpCfg c = (z == 0) ? s0 : (z == 1) ? s1 : (z == 2) ? s2 : (z == 3) ? s3 : (z == 4) ? s4 : s5;
  int gid = blockIdx.x * 4 + (threadIdx.x >> 6);
  if (gid >= c.R * c.O) return;
  int lane = threadIdx.x & 63;
  int r = gid / c.O, o = gid - r * c.O;
  const float* x = c.X + (size_t)r * ND;
  const float* wp = c.W + (size_t)o * c.wStride + c.wOff;
  float acc = 0.f;
  for (int d = lane; d < ND; d += 64) acc += x[d] * wp[d];
  acc = wave_sum(acc);
  if (lane == 0) c.Out[gid] = acc;
}

// ---------------- folds ----------------
struct FoldCfg { const float* fw; const float* fb; const float* qw; const float* qb; float* F; int O; };

__global__ __launch_bounds__(256) void k_fold1B(FoldCfg A, FoldCfg Bc)
{
  FoldCfg c = (blockIdx.y == 0) ? A : Bc;
  int O = c.O;
  int gid = blockIdx.x * 4 + (threadIdx.x >> 6);
  int lane = threadIdx.x & 63;
  if (gid >= 3 * ND) return;
  int part = gid / ND, cc0 = gid - part * ND;
  const float* qrow = c.qw + (size_t)(part * ND + cc0) * ND;
  float p0 = 0.f, p1 = 0.f, p2 = 0.f, cc = 0.f;
  for (int d = lane; d < ND; d += 64) {
    float q = qrow[d];
    p0 += c.fw[d * O + 0] * q;
    p1 += c.fw[d * O + 1] * q;
    if (O == 3) p2 += c.fw[d * O + 2] * q;
    cc += c.fb[d] * q;
  }
  p0 = wave_sum(p0); p1 = wave_sum(p1); p2 = wave_sum(p2); cc = wave_sum(cc);
  if (lane == 0) {
    c.F[OF_Pq + part * 1440 + 0 * ND + cc0] = p0;
    c.F[OF_Pq + part * 1440 + 1 * ND + cc0] = p1;
    c.F[OF_Pq + part * 1440 + 2 * ND + cc0] = (O == 3) ? p2 : 0.f;
    c.F[OF_cq + part * ND + cc0] = cc + c.qb[part * ND + cc0];
  }
}

__global__ __launch_bounds__(256) void k_fold2B(FoldCfg A, FoldCfg Bc)
{
  FoldCfg c = (blockIdx.y == 0) ? A : Bc;
  int O = c.O;
  float* F = c.F;
  int gid = blockIdx.x * 4 + (threadIdx.x >> 6);
  int lane = threadIdx.x & 63;
  if (gid < 3 * ND) {
    int part = gid / ND, cc0 = gid - part * ND;
    const float* qrow = c.qw + (size_t)(part * ND + cc0) * ND;
    const float* Pv = F + OF_Pq + 2 * 1440;
    const float* cv = F + OF_cq + 2 * ND;
    float p0 = 0.f, p1 = 0.f, p2 = 0.f, cc = 0.f;
    for (int d = lane; d < ND; d += 64) {
      float q = qrow[d];
      p0 += Pv[0 * ND + d] * q;
      p1 += Pv[1 * ND + d] * q;
      if (O == 3) p2 += Pv[2 * ND + d] * q;
      cc += cv[d] * q;
    }
    p0 = wave_sum(p0); p1 = wave_sum(p1); p2 = wave_sum(p2); cc = wave_sum(cc);
    if (lane == 0) {
      F[OF_Q2 + part * 1440 + 0 * ND + cc0] = p0;
      F[OF_Q2 + part * 1440 + 1 * ND + cc0] = p1;
      F[OF_Q2 + part * 1440 + 2 * ND + cc0] = (O == 3) ? p2 : 0.f;
      F[OF_dq + part * ND + cc0] = cc + c.qb[part * ND + cc0];
    }
  } else if (gid < 3 * ND + 16) {
    int s = gid - 3 * ND;
    const float* Pq = F + OF_Pq;
    const float* Pk = F + OF_Pq + 1440;
    const float* cq = F + OF_cq;
    const float* ck = F + OF_cq + ND;
    float acc = 0.f;
    if (s < 9) {
      int o = s / 3, op = s % 3;
      bool ok = (o < O) && (op < O);
      if (ok) for (int q = lane; q < ND; q += 64) acc += Pq[o * ND + q] * Pk[op * ND + q];
      acc = wave_sum(acc);
      if (lane == 0) F[OF_S + s] = ok ? acc : 0.f;
    } else if (s < 12) {
      int o = s - 9; bool ok = o < O;
      if (ok) for (int q = lane; q < ND; q += 64) acc += Pq[o * ND + q] * ck[q];
      acc = wave_sum(acc);
      if (lane == 0) F[OF_u + o] = ok ? acc : 0.f;
    } else if (s < 15) {
      int o = s - 12; bool ok = o < O;
      if (ok) for (int q = lane; q < ND; q += 64) acc += cq[q] * Pk[o * ND + q];
      acc = wave_sum(acc);
      if (lane == 0) F[OF_r + o] = ok ? acc : 0.f;
    } else {
      for (int q = lane; q < ND; q += 64) acc += cq[q] * ck[q];
      acc = wave_sum(acc);
      if (lane == 0) F[OF_w] = acc;
    }
  }
}

__global__ __launch_bounds__(256) void k_fold3B(FoldCfg A, FoldCfg Bc)
{
  FoldCfg c = (blockIdx.y == 0) ? A : Bc;
  int O = c.O;
  float* F = c.F;
  int s = blockIdx.x * 4 + (threadIdx.x >> 6);
  int lane = threadIdx.x & 63;
  if (s >= 16) return;
  const float* Q2 = F + OF_Q2;
  const float* K2 = F + OF_Q2 + 1440;
  const float* dq = F + OF_dq;
  const float* dk = F + OF_dq + ND;
  float acc = 0.f;
  if (s < 9) {
    int o = s / 3, op = s % 3;
    bool ok = (o < O) && (op < O);
    if (ok) for (int q = lane; q < ND; q += 64) acc += Q2[o * ND + q] * K2[op * ND + q];
    acc = wave_sum(acc);
    if (lane == 0) F[OF_S + 16 + s] = ok ? acc : 0.f;
  } else if (s < 12) {
    int o = s - 9; bool ok = o < O;
    if (ok) for (int q = lane; q < ND; q += 64) acc += Q2[o * ND + q] * dk[q];
    acc = wave_sum(acc);
    if (lane == 0) F[OF_u + 16 + o] = ok ? acc : 0.f;
  } else if (s < 15) {
    int o = s - 12; bool ok = o < O;
    if (ok) for (int q = lane; q < ND; q += 64) acc += dq[q] * K2[o * ND + q];
    acc = wave_sum(acc);
    if (lane == 0) F[OF_r + 16 + o] = ok ? acc : 0.f;
  } else {
    for (int q = lane; q < ND; q += 64) acc += dq[q] * dk[q];
    acc = wave_sum(acc);
    if (lane == 0) F[OF_w + 16] = acc;
  }
}

__global__ void k_multi(const float* __restrict__ a, const float* __restrict__ bb,
                        const float* __restrict__ bc, float* __restrict__ out)
{
  int i = blockIdx.x * blockDim.x + threadIdx.x;
  if (i >= NB * NM * NM * 2) return;
  int c = i & 1;
  int t = i >> 1;
  int n = t % NM; t /= NM;
  int m = t % NM;
  int b = t / NM;
  out[i] = a[((size_t)b * NM + m) * 2 + c] + bb[((size_t)b * NM + n) * 2 + c] + bc[c];
}

template <int O, int NVX>
static void run_rounds(hipStream_t stream,
                       float* keyb, float* valb,
                       u16* kH, u16* kL,
                       const float* kmp, const float* vmp, int vmOff, int vmStride,
                       const u16* WtHp, const u16* WtLp,
                       const float* lwp, const float* lbp,
                       float* fold, float* linK, float* linV,
                       float* tmp, float* Y1, float* Y2, float* outp,
                       const float* typeSrc, const float* keyMaskG, float* km2G, int doType)
{
  dim3 blk(256);
  for (int r = 0; r < 5; ++r) {
    k_tmpM<<<dim3(10, O, NB), blk, 0, stream>>>(kH, kL, WtHp, WtLp, tmp, O,
        typeSrc, keyMaskG, km2G, (r == 0) ? doType : 0);
    if (r < 4) {
      k_bilatt0<O, NVX><<<dim3(NB * NM), blk, 0, stream>>>(
          tmp, valb, linK, linV, lbp, fold, kmp, vmp, vmOff, vmStride, Y1);
      k_att1vupd<O, NVX><<<dim3(NB * NVX), blk, 0, stream>>>(
          Y1, Y2, fold, kmp, vmp, vmOff, vmStride, valb, lwp, linV);
      k_kupd<O, NVX><<<dim3(NB * NM), blk, 0, stream>>>(Y2, fold, keyb, lwp, linK, kH, kL);
    } else {
      k_bilfin<O, NVX><<<dim3(NB * NM), blk, 0, stream>>>(
          tmp, valb, linK, linV, lbp, kmp, vmp, vmOff, vmStride, outp);
    }
  }
}

extern "C" void kernel_launch(void* const* d_in, const int* in_sizes, int n_in,
                              void* d_out, int out_size, void* d_ws, size_t ws_size,
                              hipStream_t stream)
{
  const float* key        = (const float*)d_in[0];
  const float* value      = (const float*)d_in[1];
  const float* key_mask   = (const float*)d_in[2];
  const float* value_mask = (const float*)d_in[3];
  const float* w_kt = (const float*)d_in[4];  const float* b_kt = (const float*)d_in[5];
  const float* w_vt = (const float*)d_in[6];  const float* b_vt = (const float*)d_in[7];
  const float* w_km = (const float*)d_in[8];  const float* b_km = (const float*)d_in[9];
  const float* w_vm = (const float*)d_in[10]; const float* b_vm = (const float*)d_in[11];
  const float* w_ks = (const float*)d_in[12]; const float* b_ks = (const float*)d_in[13];
  const float* w_vs = (const float*)d_in[14]; const float* b_vs = (const float*)d_in[15];
  const float* bt_W = (const float*)d_in[16]; const float* bt_lw = (const float*)d_in[17];
  const float* bt_lb = (const float*)d_in[18];
  const float* bi_W = (const float*)d_in[19]; const float* bi_lw = (const float*)d_in[20];
  const float* bi_lb = (const float*)d_in[21];
  const float* w_ffnt = (const float*)d_in[22]; const float* b_ffnt = (const float*)d_in[23];
  const float* w_ffn  = (const float*)d_in[24]; const float* b_ffn  = (const float*)d_in[25];
  const float* qkvt_w = (const float*)d_in[26]; const float* qkvt_b = (const float*)d_in[27];
  const float* qkv_w  = (const float*)d_in[28]; const float* qkv_b  = (const float*)d_in[29];
  const float* w_cls  = (const float*)d_in[30]; const float* b_cls  = (const float*)d_in[31];

  float* ws = (float*)d_ws;
  size_t off = 0;
  auto alloc = [&](size_t nfloat) { float* p = ws + off; off += (nfloat + 3) & ~(size_t)3; return p; };

  float* kt_t   = alloc((size_t)NB * NM * ND);
  float* vt_t   = alloc((size_t)NB * NNV * ND);
  float* kt_s   = alloc((size_t)NB * NM * ND);
  float* vt_s   = alloc((size_t)NB * NM * ND);
  float* tmp    = alloc((size_t)NB * 3 * NM * ND);
  float* Y1     = alloc((size_t)NB * NM * NNV * 3);
  float* Y2     = alloc((size_t)NB * NM * NNV * 3);
  float* linK_t = alloc((size_t)NB * NM * 3);
  float* linV_t = alloc((size_t)NB * NNV * 3);
  float* linK_s = alloc((size_t)NB * NM * 3);
  float* linV_s = alloc((size_t)NB * NM * 3);
  float* fold_t = alloc(FOLD_SZ);
  float* fold_s = alloc(FOLD_SZ);
  float* km2    = alloc((size_t)NB * NM);
  float* a2     = alloc((size_t)NB * NM * 2);
  float* b2     = alloc((size_t)NB * NM * 2);
  u16* WtH = (u16*)alloc((size_t)5 * ND * ND / 2);
  u16* WtL = (u16*)alloc((size_t)5 * ND * ND / 2);
  u16* keyH_t = (u16*)alloc((size_t)NB * NM * ND / 2);
  u16* keyL_t = (u16*)alloc((size_t)NB * NM * ND / 2);
  u16* keyH_s = (u16*)alloc((size_t)NB * NM * ND / 2);
  u16* keyL_s = (u16*)alloc((size_t)NB * NM * ND / 2);
  // input planes (key/value) and 6 projection-weight planes
  u16* inKH = (u16*)alloc((size_t)NB * NM * NH / 2);
  u16* inKL = (u16*)alloc((size_t)NB * NM * NH / 2);
  u16* inVH = (u16*)alloc((size_t)NB * NNV * NH / 2);
  u16* inVL = (u16*)alloc((size_t)NB * NNV * NH / 2);
  u16* WPH  = (u16*)alloc((size_t)6 * ND * NH / 2);
  u16* WPL  = (u16*)alloc((size_t)6 * ND * NH / 2);
  (void)ws_size; (void)in_sizes; (void)n_in; (void)out_size;

  float* kmf = tmp;                               // projections done before rounds use tmp
  float* vmf = tmp + (size_t)NB * NM * ND;

  float* out_type   = (float*)d_out;
  float* out_multi  = out_type + (size_t)NB * NM * NNV * 3;
  float* out_single = out_multi + (size_t)NB * NM * NM * 2;

  dim3 blk(256);

  // ---- one-time conversions: 5 W^T planes + 6 weights + key + value (single launch) ----
  const float* wsrc[6] = { w_kt, w_vt, w_ks, w_vs, w_km, w_vm };
  CvtAll CA;
  for (int i = 0; i < 6; ++i) {
    CA.j[i].s = wsrc[i];
    CA.j[i].h = WPH + (size_t)i * ND * NH;
    CA.j[i].l = WPL + (size_t)i * ND * NH;
    CA.j[i].n4 = ND * NH / 4;
  }
  CA.j[6] = { key,   inKH, inKL, NB * NM * NH / 4 };
  CA.j[7] = { value, inVH, inVL, NB * NNV * NH / 4 };
  k_cvtAll<<<dim3(15, 15, 13), blk, 0, stream>>>(bt_W, bi_W, WtH, WtL, CA);

  // ---- all 6 big projections, one MFMA launch (fully plane-based) ----
  Proj6 P;
  P.c[0] = { inKH, inKL, WPH + 0*(size_t)ND*NH, WPL + 0*(size_t)ND*NH, b_kt, kt_t, keyH_t, keyL_t, NB * NM,  0, NM,  NM * NH };
  P.c[1] = { inVH, inVL, WPH + 1*(size_t)ND*NH, WPL + 1*(size_t)ND*NH, b_vt, vt_t, nullptr, nullptr, NB * NNV, 0, NNV, NNV * NH };
  P.c[2] = { inKH, inKL, WPH + 2*(size_t)ND*NH, WPL + 2*(size_t)ND*NH, b_ks, kt_s, keyH_s, keyL_s, NB * NM,  0, NM,  NM * NH };
  P.c[3] = { inVH, inVL, WPH + 3*(size_t)ND*NH, WPL + 3*(size_t)ND*NH, b_vs, vt_s, nullptr, nullptr, NB * NM,  1, NM,  NNV * NH };
  P.c[4] = { inKH, inKL, WPH + 4*(size_t)ND*NH, WPL + 4*(size_t)ND*NH, b_km, kmf,  nullptr, nullptr, NB * NM,  0, NM,  NM * NH };
  P.c[5] = { inVH, inVL, WPH + 5*(size_t)ND*NH, WPL + 5*(size_t)ND*NH, b_vm, vmf,  nullptr, nullptr, NB * NM,  1, NM,  NNV * NH };
  k_projM<<<dim3(193 * 10), blk, 0, stream>>>(P, NH);

  // ---- folds for both paths (batched) ----
  FoldCfg ft = { w_ffnt, b_ffnt, qkvt_w, qkvt_b, fold_t, 3 };
  FoldCfg fs = { w_ffn,  b_ffn,  qkv_w,  qkv_b,  fold_s, 2 };
  k_fold1B<<<dim3(360, 2), blk, 0, stream>>>(ft, fs);
  k_fold2B<<<dim3(364, 2), blk, 0, stream>>>(ft, fs);
  k_fold3B<<<dim3(4, 2), blk, 0, stream>>>(ft, fs);

  // ---- all small matvecs, one launch ----
  SpCfg s0 = { kt_t, bt_lw, linK_t, NB * NM,  3, 2 * ND, 0 };
  SpCfg s1 = { vt_t, bt_lw, linV_t, NB * NNV, 3, 2 * ND, ND };
  SpCfg s2 = { kt_s, bi_lw, linK_s, NB * NM,  2, 2 * ND, 0 };
  SpCfg s3 = { vt_s, bi_lw, linV_s, NB * NM,  2, 2 * ND, ND };
  SpCfg s4 = { kmf,  w_cls, a2,     NB * NM,  2, 2 * ND, 0 };
  SpCfg s5 = { vmf,  w_cls, b2,     NB * NM,  2, 2 * ND, ND };
  k_sproj6<<<dim3((NB * NNV * 3 + 3) / 4, 6), blk, 0, stream>>>(s0, s1, s2, s3, s4, s5);

  // multi logits (independent of rounds)
  k_multi<<<dim3((NB * NM * NM * 2 + 255) / 256), blk, 0, stream>>>(a2, b2, b_cls, out_multi);

  // ---- type path rounds ----
  run_rounds<3, NNV>(stream, kt_t, vt_t, keyH_t, keyL_t, key_mask, value_mask, 0, NNV,
                     WtH, WtL, bt_lw, bt_lb, fold_t, linK_t, linV_t,
                     tmp, Y1, Y2, out_type, nullptr, nullptr, nullptr, 0);

  // ---- single path rounds (first tmpM computes km2 from out_type in its epilogue) ----
  run_rounds<2, NM>(stream, kt_s, vt_s, keyH_s, keyL_s, km2, value_mask, 1, NNV,
                    WtH + (size_t)3 * ND * ND, WtL + (size_t)3 * ND * ND,
                    bi_lw, bi_lb, fold_s, linK_s, linV_s,
                    tmp, Y1, Y2, out_single, out_type, key_mask, km2, 1);
}